// Round 4
// baseline (1716.346 us; speedup 1.0000x reference)
//
#include <hip/hip_runtime.h>
#include <cstdint>

typedef _Float16 f16;
typedef _Float16 f16x8 __attribute__((ext_vector_type(8)));
typedef _Float16 f16x4 __attribute__((ext_vector_type(4)));
typedef float    f32x4 __attribute__((ext_vector_type(4)));
typedef float    f32x16 __attribute__((ext_vector_type(16)));

#define DIMN 1024
#define BATCH 32768
#define NLAYERS 18
#define NBLOCKS 6

// ---- async global->LDS, 16B per lane ----
__device__ __forceinline__ void gl2lds16(const f16* g, const f16* l) {
    auto gp = (const __attribute__((address_space(1))) unsigned int*)(uintptr_t)g;
    auto lp = (__attribute__((address_space(3))) unsigned int*)(uintptr_t)l;
    __builtin_amdgcn_global_load_lds(gp, lp, 16, 0, 0);
}

// ---- convert fp32 x -> fp16 ----
__global__ void cvt_kernel(const float* __restrict__ x, f16* __restrict__ o) {
    int i = (blockIdx.x * 256 + threadIdx.x) * 4;
    float4 v = *(const float4*)&x[i];
    f16x4 r;
    r[0] = (f16)v.x; r[1] = (f16)v.y; r[2] = (f16)v.z; r[3] = (f16)v.w;
    *(f16x4*)&o[i] = r;
}

// ---- W_eff = dequant(int4, group-16 scales) + lb@la, fp16 output ----
__global__ __launch_bounds__(256) void prep_w_kernel(
        const int* __restrict__ qw, const float* __restrict__ sc,
        const float* __restrict__ la, const float* __restrict__ lb,
        f16* __restrict__ W) {
    int b = blockIdx.x;
    int li = b >> 7;
    int og = (b & 127) << 3;  // first of 8 rows
    __shared__ float lbs[8][32];
    int tid = threadIdx.x;
    lbs[tid >> 5][tid & 31] = lb[((size_t)li * 1024 + og + (tid >> 5)) * 32 + (tid & 31)];
    __syncthreads();

    int i0 = tid * 4;  // 4 cols per thread
    const float* laL = la + (size_t)li * 32 * 1024;
    float acc[8][4] = {};
    for (int r = 0; r < 32; ++r) {
        float4 lav = *(const float4*)&laL[r * 1024 + i0];
#pragma unroll
        for (int q = 0; q < 8; ++q) {
            float wv = lbs[q][r];
            acc[q][0] += wv * lav.x; acc[q][1] += wv * lav.y;
            acc[q][2] += wv * lav.z; acc[q][3] += wv * lav.w;
        }
    }
#pragma unroll
    for (int q = 0; q < 8; ++q) {
        size_t row = (size_t)li * 1024 + og + q;
        size_t rowbase = row * 1024;
        int4 code = *(const int4*)&qw[rowbase + i0];
        float scale = sc[row * 64 + (i0 >> 4)];
        f16x4 o;
        o[0] = (f16)((float)code.x * scale + acc[q][0]);
        o[1] = (f16)((float)code.y * scale + acc[q][1]);
        o[2] = (f16)((float)code.z * scale + acc[q][2]);
        o[3] = (f16)((float)code.w * scale + acc[q][3]);
        *(f16x4*)&W[rowbase + i0] = o;
    }
}

// ---- main GEMM: C[M,1024] = A[M,1024] @ W^T + bias, optional relu, fp16 out ----
// 32x32x16 MFMA, k-step-16 phases, register ping-pong fragments, 4-deep LDS
// pipeline (4 slots x 32KB), counted vmcnt(4)/lgkmcnt(6), one barrier/phase.
// LDS tile layout (bank-conflict-free, 128B rows): phys row R (0..127) of each
// 16KB region holds m-rows {R, R+128}; logical (half h, kchunk c) at phys
// 16B-slot (h*4+c) ^ (R&7). Staging: linear gl2lds dest + inverse-permuted
// global source (rule 21). Frag read: 8 lanes -> 8 distinct slots -> 32 banks.
__global__ __launch_bounds__(512, 2) void gemm_kernel(
        const f16* __restrict__ A, const f16* __restrict__ W,
        const float* __restrict__ bias, f16* __restrict__ C, int relu) {
    __shared__ __align__(16) char smem[131072];

    int tid = threadIdx.x;
    int l = tid & 63, w = tid >> 6;
    int wm = w >> 2, wn = w & 3;   // wave grid 2(M) x 4(N); wave tile 128x64
    int m_l = l & 31;
    int kg = l >> 5;               // k-group within k-step (operand k = kg*8..+7)

    // XCD-bijective swizzle: 512 wgs -> 64/XCD; 4 n-tiles of an m-tile adjacent
    int hb = blockIdx.x;
    int xcd = hb & 7, idx = hb >> 3;
    int mt = xcd * 16 + (idx >> 2);
    int nt = idx & 3;
    int bm = mt * 256, bn = nt * 256;

    // ---- staging: thread t -> phys row R0 = t>>3 (+64 on 2nd call), phys slot
    // t&7. Stored logical = (t&7) ^ (R&7)  (R&7 invariant under +64) ->
    // h = logical>>2 (which 128-row half), kchunk = logical&3 (8-f16 chunk).
    int R0 = tid >> 3;
    int lgc = (tid & 7) ^ (R0 & 7);
    int hh = lgc >> 2, kch = lgc & 3;
    const f16* pA = A + (size_t)(bm + hh * 128 + R0) * 1024 + kch * 8;
    const f16* pB = W + (size_t)(bn + hh * 128 + R0) * 1024 + kch * 8;
    int ld0 = tid * 16;

#define STGA(SL, KT) do { \
    gl2lds16(pA + (KT) * 32, (const f16*)(smem + (SL) * 32768 + ld0)); \
    gl2lds16(pA + 65536 + (KT) * 32, (const f16*)(smem + (SL) * 32768 + 8192 + ld0)); } while (0)
#define STGB(SL, KT) do { \
    gl2lds16(pB + (KT) * 32, (const f16*)(smem + (SL) * 32768 + 16384 + ld0)); \
    gl2lds16(pB + 65536 + (KT) * 32, (const f16*)(smem + (SL) * 32768 + 24576 + ld0)); } while (0)

    // ---- fragment read offsets (swizzled, 128B rows) ----
    // A: m = wm*128 + mf*32 + m_l -> R = mf*32+m_l, h = wm.
    // B: n = wn*64 + nf*32 + m_l  -> R = (wn&1)*64+nf*32+m_l, h = wn>>1.
    int aoff[4], boff[2];
#pragma unroll
    for (int mf = 0; mf < 4; ++mf) aoff[mf] = (mf * 32 + m_l) * 128;
#pragma unroll
    for (int nf = 0; nf < 2; ++nf) boff[nf] = 16384 + ((wn & 1) * 64 + nf * 32 + m_l) * 128;
    int r7 = m_l & 7;
    int sa0 = ((wm * 4 + 0 + kg) ^ r7) * 16;         // A, k-step 0
    int sa1 = ((wm * 4 + 2 + kg) ^ r7) * 16;         // A, k-step 1
    int sb0 = (((wn >> 1) * 4 + 0 + kg) ^ r7) * 16;  // B, k-step 0
    int sb1 = (((wn >> 1) * 4 + 2 + kg) ^ r7) * 16;  // B, k-step 1

    f16x8 aE[4], bE[2], aO[4], bO[2];
    f32x16 acc[4][2] = {};

#define READS(DA, DB, SBASE, SA, SB) do { _Pragma("unroll") \
    for (int mf = 0; mf < 4; ++mf) DA[mf] = *(const f16x8*)(smem + (SBASE) + aoff[mf] + (SA)); \
    _Pragma("unroll") \
    for (int nf = 0; nf < 2; ++nf) DB[nf] = *(const f16x8*)(smem + (SBASE) + boff[nf] + (SB)); } while (0)

    // swapped operands: mfma(bf, af) -> lane holds m = l&31 fixed (cols),
    // n = (reg&3) + 8*(reg>>2) + 4*kg (4 consecutive n per reg-quad)
#define MMA8(AF, BF) do { _Pragma("unroll") \
    for (int mf = 0; mf < 4; ++mf) { _Pragma("unroll") \
      for (int nf = 0; nf < 2; ++nf) \
        acc[mf][nf] = __builtin_amdgcn_mfma_f32_32x32x16_f16(BF[nf], AF[mf], acc[mf][nf], 0, 0, 0); } } while (0)

#define WAITS do { \
    asm volatile("s_waitcnt vmcnt(4) lgkmcnt(6)" ::: "memory"); \
    __builtin_amdgcn_sched_barrier(0); \
    __builtin_amdgcn_s_barrier(); \
    __builtin_amdgcn_sched_barrier(0); } while (0)

#define PHASES(T4, DT) do { \
    int kp = ((T4) + (DT) + 3) & 31; \
    /* even phase: MFMA(tile, k0) ; read (tile, k1) ; stage A(tile+3) */ \
    READS(aO, bO, ((DT) & 3) * 32768, sa1, sb1); \
    STGA(((DT) + 3) & 3, kp); \
    WAITS; \
    __builtin_amdgcn_s_setprio(1); \
    MMA8(aE, bE); \
    __builtin_amdgcn_s_setprio(0); \
    __builtin_amdgcn_sched_barrier(0); \
    /* odd phase: MFMA(tile, k1) ; read (tile+1, k0) ; stage B(tile+3) */ \
    READS(aE, bE, (((DT) + 1) & 3) * 32768, sa0, sb0); \
    STGB(((DT) + 3) & 3, kp); \
    WAITS; \
    __builtin_amdgcn_s_setprio(1); \
    MMA8(aO, bO); \
    __builtin_amdgcn_s_setprio(0); \
    __builtin_amdgcn_sched_barrier(0); \
  } while (0)

    // ---- prologue: stage tiles 0,1,2; drain tiles 0,1; preload (t0, k0) ----
    STGA(0, 0); STGB(0, 0);
    STGA(1, 1); STGB(1, 1);
    STGA(2, 2); STGB(2, 2);
    asm volatile("s_waitcnt vmcnt(4)" ::: "memory");
    __builtin_amdgcn_s_barrier();
    READS(aE, bE, 0, sa0, sb0);

    // ---- main loop: 32 K-tiles, 2 phases each; slots period-4 ----
#pragma unroll 1
    for (int t4 = 0; t4 < 32; t4 += 4) {
        PHASES(t4, 0);
        PHASES(t4, 1);
        PHASES(t4, 2);
        PHASES(t4, 3);
    }

    // ---- epilogue: bias+relu, pack 4 consecutive cols -> ds_write_b64 ----
    __syncthreads();
    f16* Cs = (f16*)smem;
    float4 bsv[2][4];
#pragma unroll
    for (int nf = 0; nf < 2; ++nf)
#pragma unroll
        for (int g = 0; g < 4; ++g)
            bsv[nf][g] = *(const float4*)&bias[bn + wn * 64 + nf * 32 + g * 8 + kg * 4];

    int c8 = (tid & 31) * 8, rr = tid >> 5;
#pragma unroll
    for (int pass = 0; pass < 2; ++pass) {
        if (wm == pass) {
#pragma unroll
            for (int mf = 0; mf < 4; ++mf) {
                int row = mf * 32 + m_l;
#pragma unroll
                for (int nf = 0; nf < 2; ++nf)
#pragma unroll
                    for (int g = 0; g < 4; ++g) {
                        float4 vb = bsv[nf][g];
                        float v0 = acc[mf][nf][g * 4 + 0] + vb.x;
                        float v1 = acc[mf][nf][g * 4 + 1] + vb.y;
                        float v2 = acc[mf][nf][g * 4 + 2] + vb.z;
                        float v3 = acc[mf][nf][g * 4 + 3] + vb.w;
                        if (relu) {
                            v0 = fmaxf(v0, 0.f); v1 = fmaxf(v1, 0.f);
                            v2 = fmaxf(v2, 0.f); v3 = fmaxf(v3, 0.f);
                        }
                        f16x4 pk;
                        pk[0] = (f16)v0; pk[1] = (f16)v1; pk[2] = (f16)v2; pk[3] = (f16)v3;
                        *(f16x4*)&Cs[row * 264 + wn * 64 + nf * 32 + g * 8 + kg * 4] = pk;
                    }
            }
        }
        __syncthreads();
#pragma unroll
        for (int it = 0; it < 8; ++it) {
            int rowr = rr + it * 16;
            f16x8 val = *(const f16x8*)&Cs[rowr * 264 + c8];
            *(f16x8*)&C[(size_t)(bm + pass * 128 + rowr) * 1024 + bn + c8] = val;
        }
        if (pass == 0) __syncthreads();
    }
}

// ---- residual + layernorm (mode 0) or final residual fp32 out (mode 1) ----
__global__ void res_ln_kernel(const f16* __restrict__ y, f16* __restrict__ h,
                              const float* __restrict__ g, const float* __restrict__ b,
                              float* __restrict__ outF, int mode) {
    int row = blockIdx.x;
    int tid = threadIdx.x;
    int c0 = tid * 4;
    const f16* yr = y + (size_t)row * DIMN;
    f16* hr = h + (size_t)row * DIMN;

    f16x4 yv = *(const f16x4*)&yr[c0];
    f16x4 hv = *(const f16x4*)&hr[c0];
    float v[4];
    float s = 0.f, sq = 0.f;
#pragma unroll
    for (int i = 0; i < 4; ++i) {
        v[i] = (float)yv[i] + (float)hv[i];
        s += v[i]; sq += v[i] * v[i];
    }
#pragma unroll
    for (int o = 32; o > 0; o >>= 1) {
        s += __shfl_xor(s, o);
        sq += __shfl_xor(sq, o);
    }
    __shared__ float red[8];
    int wv = tid >> 6, ln = tid & 63;
    if (ln == 0) { red[wv] = s; red[4 + wv] = sq; }
    __syncthreads();
    float S1 = red[0] + red[1] + red[2] + red[3];
    float S2 = red[4] + red[5] + red[6] + red[7];
    float mu = S1 * (1.f / 1024.f);
    float var = S2 * (1.f / 1024.f) - mu * mu;
    float rs = rsqrtf(var + 1e-5f);

    if (mode == 0) {
        float4 gv = *(const float4*)&g[c0];
        float4 bv = *(const float4*)&b[c0];
        f16x4 outv;
        outv[0] = (f16)((v[0] - mu) * rs * gv.x + bv.x);
        outv[1] = (f16)((v[1] - mu) * rs * gv.y + bv.y);
        outv[2] = (f16)((v[2] - mu) * rs * gv.z + bv.z);
        outv[3] = (f16)((v[3] - mu) * rs * gv.w + bv.w);
        *(f16x4*)&hr[c0] = outv;
    } else {
        float4 ov;
        ov.x = v[0]; ov.y = v[1]; ov.z = v[2]; ov.w = v[3];
        *(float4*)&outF[(size_t)row * DIMN + c0] = ov;
    }
}

extern "C" void kernel_launch(void* const* d_in, const int* in_sizes, int n_in,
                              void* d_out, int out_size, void* d_ws, size_t ws_size,
                              hipStream_t stream) {
    const float* x    = (const float*)d_in[0];
    const int*   qw   = (const int*)d_in[1];
    const float* sc   = (const float*)d_in[2];
    const float* bias = (const float*)d_in[3];
    const float* la   = (const float*)d_in[4];
    const float* lb   = (const float*)d_in[5];
    const float* lng  = (const float*)d_in[6];
    const float* lnb  = (const float*)d_in[7];
    float* out = (float*)d_out;

    char* ws = (char*)d_ws;
    f16* Weff = (f16*)ws;                                   // 37,748,736 B
    f16* H    = (f16*)(ws + (size_t)37748736);              // 67,108,864 B
    f16* P    = (f16*)(ws + (size_t)37748736 + 67108864);   // 67,108,864 B
    f16* Q    = (f16*)d_out;                                // scratch alias (dead before final fp32 write)

    cvt_kernel<<<BATCH * DIMN / (256 * 4), 256, 0, stream>>>(x, H);
    prep_w_kernel<<<NLAYERS * 128, 256, 0, stream>>>(qw, sc, la, lb, Weff);

    for (int blk = 0; blk < NBLOCKS; ++blk) {
        for (int j = 0; j < 3; ++j) {
            int li = blk * 3 + j;
            const f16* in = (j == 0) ? H : ((j == 1) ? P : Q);
            f16* o = (j == 1) ? Q : P;
            gemm_kernel<<<512, 512, 0, stream>>>(
                in, Weff + ((size_t)li << 20), bias + li * 1024, o, (j < 2) ? 1 : 0);
        }
        int lnidx = (blk < 5) ? blk : 4;  // unused in mode 1
        res_ln_kernel<<<BATCH, 256, 0, stream>>>(
            P, H, lng + lnidx * 1024, lnb + lnidx * 1024, out, (blk == 5) ? 1 : 0);
    }
}